// Round 1
// baseline (549.869 us; speedup 1.0000x reference)
//
#include <hip/hip_runtime.h>
#include <hip/hip_bf16.h>
#include <stdint.h>

#define N_NODES 100000
#define N_EDGES 320000
#define DIM 128
#define AGG_EPS 1e-6f
#define BN_EPS 1e-5f
#define NODE_BLOCKS 2048

typedef float f32x4 __attribute__((ext_vector_type(4)));
typedef __bf16 bf16x8 __attribute__((ext_vector_type(8)));

__device__ __forceinline__ uint32_t f2bf(float f) {
  union { float f; uint32_t u; } v; v.f = f;
  uint32_t u = v.u;
  return (u + 0x7fffu + ((u >> 16) & 1u)) >> 16;  // RNE
}
__device__ __forceinline__ float bf2f(uint32_t h) {
  union { uint32_t u; float f; } v; v.u = h << 16;
  return v.f;
}

// ---------------- K0: weights -> transposed combined bf16 [512][128] ----------------
__global__ __launch_bounds__(256) void k_prep(
    const float* __restrict__ Wa, const float* __restrict__ ba,
    const float* __restrict__ Wb, const float* __restrict__ bb,
    const float* __restrict__ Wd, const float* __restrict__ bd,
    const float* __restrict__ We, const float* __restrict__ be,
    ushort* __restrict__ wt, float* __restrict__ biasc) {
  int t = blockIdx.x * 256 + threadIdx.x;  // 65536 = 512*128
  int n = t >> 7, k = t & 127;
  int sel = n >> 7, j = n & 127;
  const float* W = (sel == 0) ? Wa : (sel == 1) ? Wb : (sel == 2) ? Wd : We;
  wt[n * 128 + k] = (ushort)f2bf(W[k * 128 + j]);  // Wt[n][k] = W[k][n]
  if (t < 512) {
    int s2 = t >> 7;
    const float* b = (s2 == 0) ? ba : (s2 == 1) ? bb : (s2 == 2) ? bd : be;
    biasc[t] = b[t & 127];
  }
}

// ---------------- K1: ABDE[100000][512] bf16 = bf16(x) @ Wc + bias ----------------
// BM=64 rows per block, loop 8 N-tiles of 64. A and B tiles in LDS, XOR-swizzled
// ((row&7)<<4) per guide G4 to kill the stride-256B ds_read_b128 bank conflict.
__global__ __launch_bounds__(256) void k_gemm(
    const float* __restrict__ x, const ushort* __restrict__ wt,
    const float* __restrict__ biasc, ushort* __restrict__ abde) {
  __shared__ ushort As[64 * 128];
  __shared__ ushort Bs[64 * 128];
  const int tid = threadIdx.x;
  const int m0 = blockIdx.x * 64;

  // stage A: 64x128 fp32 -> bf16, 1024 16B quads, coalesced
#pragma unroll
  for (int i = 0; i < 4; ++i) {
    int qid = tid + 256 * i;
    int row = qid >> 4, q = qid & 15;
    int gr = m0 + row;
    uint4 pk = make_uint4(0u, 0u, 0u, 0u);
    if (gr < N_NODES) {
      const float* s = x + gr * 128 + q * 8;
      float4 f0 = *(const float4*)(s);
      float4 f1 = *(const float4*)(s + 4);
      pk.x = f2bf(f0.x) | (f2bf(f0.y) << 16);
      pk.y = f2bf(f0.z) | (f2bf(f0.w) << 16);
      pk.z = f2bf(f1.x) | (f2bf(f1.y) << 16);
      pk.w = f2bf(f1.z) | (f2bf(f1.w) << 16);
    }
    int byte = (row * 256 + q * 16) ^ ((row & 7) << 4);
    *(uint4*)((char*)As + byte) = pk;
  }
  __syncthreads();

  const int w = tid >> 6, lane = tid & 63;
  const int r = lane & 15, g = lane >> 4;
  const int arow = w * 16 + r;

  // hoist A fragments (reused across all 8 N-tiles)
  bf16x8 afrag[4];
#pragma unroll
  for (int kk = 0; kk < 4; ++kk) {
    int ab = (arow * 256 + kk * 64 + g * 16) ^ ((arow & 7) << 4);
    afrag[kk] = *(const bf16x8*)((const char*)As + ab);
  }

  for (int nt = 0; nt < 8; ++nt) {
    const int n0 = nt * 64;
    __syncthreads();
    // stage B tile: Wt rows n0..n0+63 (bf16, L2-resident), 1024 quads
#pragma unroll
    for (int i = 0; i < 4; ++i) {
      int qid = tid + 256 * i;
      int row = qid >> 4, q = qid & 15;
      uint4 v = *(const uint4*)(wt + (n0 + row) * 128 + q * 8);
      int byte = (row * 256 + q * 16) ^ ((row & 7) << 4);
      *(uint4*)((char*)Bs + byte) = v;
    }
    __syncthreads();

    f32x4 acc[4] = {{0.f,0.f,0.f,0.f},{0.f,0.f,0.f,0.f},{0.f,0.f,0.f,0.f},{0.f,0.f,0.f,0.f}};
#pragma unroll
    for (int kk = 0; kk < 4; ++kk) {
#pragma unroll
      for (int n = 0; n < 4; ++n) {
        int brow = n * 16 + r;
        int bb = (brow * 256 + kk * 64 + g * 16) ^ ((brow & 7) << 4);
        bf16x8 bv = *(const bf16x8*)((const char*)Bs + bb);
        acc[n] = __builtin_amdgcn_mfma_f32_16x16x32_bf16(afrag[kk], bv, acc[n], 0, 0, 0);
      }
    }
    // epilogue: C/D layout col=lane&15, row=(lane>>4)*4+q (m89-verified)
#pragma unroll
    for (int n = 0; n < 4; ++n) {
      int col = n0 + n * 16 + r;
      float bias = biasc[col];
#pragma unroll
      for (int q = 0; q < 4; ++q) {
        int row = m0 + w * 16 + g * 4 + q;
        if (row < N_NODES) abde[row * 512 + col] = (ushort)f2bf(acc[n][q] + bias);
      }
    }
  }
}

// ---------------- CSR build ----------------
__global__ __launch_bounds__(256) void k_count(const int* __restrict__ dst,
                                               int* __restrict__ cnt) {
  int t = blockIdx.x * 256 + threadIdx.x;
  if (t < N_EDGES) atomicAdd(&cnt[dst[t]], 1);
}

__global__ __launch_bounds__(1024) void k_scan(const int* __restrict__ cnt,
                                               int* __restrict__ row_ptr,
                                               int* __restrict__ cursor) {
  __shared__ int sums[1024];
  const int t = threadIdx.x;
  const int CH = 98;  // 1024*98 >= 100000
  int base = t * CH;
  int s = 0;
  for (int j = 0; j < CH; ++j) {
    int idx = base + j;
    if (idx < N_NODES) s += cnt[idx];
  }
  sums[t] = s;
  __syncthreads();
  for (int off = 1; off < 1024; off <<= 1) {
    int v = (t >= off) ? sums[t - off] : 0;
    __syncthreads();
    sums[t] += v;
    __syncthreads();
  }
  int run = (t == 0) ? 0 : sums[t - 1];
  for (int j = 0; j < CH; ++j) {
    int idx = base + j;
    if (idx < N_NODES) {
      row_ptr[idx] = run;
      cursor[idx] = run;
      run += cnt[idx];
    }
  }
  if (t == 1023) row_ptr[N_NODES] = run;
}

__global__ __launch_bounds__(256) void k_scatter(const int* __restrict__ dst,
                                                 int* __restrict__ cursor,
                                                 int* __restrict__ csr_eid) {
  int t = blockIdx.x * 256 + threadIdx.x;
  if (t < N_EDGES) {
    int d = dst[t];
    int pos = atomicAdd(&cursor[d], 1);
    csr_eid[pos] = t;
  }
}

// ---------------- K5: wave-per-node fused edge+aggregate+h+BN-partials ----------------
__global__ __launch_bounds__(256) void k_node(
    const ushort* __restrict__ abde, const int* __restrict__ row_ptr,
    const int* __restrict__ csr_eid, const int* __restrict__ esrc,
    float* __restrict__ out_e, ushort* __restrict__ h,
    float* __restrict__ partials) {
  const int tid = threadIdx.x;
  const int lane = tid & 63;
  const int wid = (blockIdx.x << 2) | (tid >> 6);
  const int nw = NODE_BLOCKS * 4;
  float s0 = 0.f, s1 = 0.f, q0 = 0.f, q1 = 0.f;
  for (int i = wid; i < N_NODES; i += nw) {
    uint32_t axu = *(const uint32_t*)(abde + i * 512 + 2 * lane);        // Ax
    uint32_t dxu = *(const uint32_t*)(abde + i * 512 + 256 + 2 * lane);  // Dx
    float ax0 = bf2f(axu & 0xffffu), ax1 = bf2f(axu >> 16);
    float dx0 = bf2f(dxu & 0xffffu), dx1 = bf2f(dxu >> 16);
    float n0 = 0.f, n1 = 0.f, d0 = 0.f, d1 = 0.f;
    int ke = row_ptr[i + 1];
    for (int k = row_ptr[i]; k < ke; ++k) {
      int eid = csr_eid[k];
      int src = esrc[eid];
      uint32_t exu = *(const uint32_t*)(abde + src * 512 + 384 + 2 * lane);  // Ex
      uint32_t bxu = *(const uint32_t*)(abde + src * 512 + 128 + 2 * lane);  // Bx
      float e0 = dx0 + bf2f(exu & 0xffffu);
      float e1 = dx1 + bf2f(exu >> 16);
      *(float2*)(out_e + (size_t)eid * 128 + 2 * lane) = make_float2(e0, e1);
      float sg0 = 1.f / (1.f + __expf(-e0));
      float sg1 = 1.f / (1.f + __expf(-e1));
      n0 += sg0 * bf2f(bxu & 0xffffu);
      n1 += sg1 * bf2f(bxu >> 16);
      d0 += sg0; d1 += sg1;
    }
    float h0 = ax0 + n0 / (d0 + AGG_EPS);
    float h1 = ax1 + n1 / (d1 + AGG_EPS);
    *(uint32_t*)(h + i * 128 + 2 * lane) = f2bf(h0) | (f2bf(h1) << 16);
    s0 += h0; s1 += h1; q0 += h0 * h0; q1 += h1 * h1;
  }
  __shared__ float red[256 * 4];
  red[tid] = s0; red[256 + tid] = s1; red[512 + tid] = q0; red[768 + tid] = q1;
  __syncthreads();
  if (tid < 64) {
    float vs0 = red[tid] + red[tid + 64] + red[tid + 128] + red[tid + 192];
    float vs1 = red[256 + tid] + red[256 + tid + 64] + red[256 + tid + 128] + red[256 + tid + 192];
    float vq0 = red[512 + tid] + red[512 + tid + 64] + red[512 + tid + 128] + red[512 + tid + 192];
    float vq1 = red[768 + tid] + red[768 + tid + 64] + red[768 + tid + 128] + red[768 + tid + 192];
    float* p = partials + blockIdx.x * 256;
    p[2 * tid] = vs0;
    p[2 * tid + 1] = vs1;
    p[128 + 2 * tid] = vq0;
    p[128 + 2 * tid + 1] = vq1;
  }
}

// ---------------- K6: BN stats ----------------
__global__ __launch_bounds__(128) void k_stats(const float* __restrict__ partials,
                                               float* __restrict__ stats) {
  int c = threadIdx.x;
  float s = 0.f, q = 0.f;
  for (int b = 0; b < NODE_BLOCKS; ++b) {
    s += partials[b * 256 + c];
    q += partials[b * 256 + 128 + c];
  }
  float mean = s * (1.f / (float)N_NODES);
  float var = q * (1.f / (float)N_NODES) - mean * mean;
  stats[c] = mean;
  stats[128 + c] = rsqrtf(var + BN_EPS);
}

// ---------------- K7: normalize + ReLU ----------------
__global__ __launch_bounds__(256) void k_final(const ushort* __restrict__ h,
    const float* __restrict__ gamma, const float* __restrict__ beta,
    const float* __restrict__ stats, float* __restrict__ out_x) {
  int idx = blockIdx.x * 256 + threadIdx.x;  // 1,600,000 units of 8 elems
  int c = (idx & 15) * 8;
  uint4 hv = *(const uint4*)(h + idx * 8);
  uint32_t hw[4] = {hv.x, hv.y, hv.z, hv.w};
  float out[8];
#pragma unroll
  for (int j = 0; j < 8; ++j) {
    uint32_t u = (j & 1) ? (hw[j >> 1] >> 16) : (hw[j >> 1] & 0xffffu);
    float hf = bf2f(u);
    int cc = c + j;
    float v = gamma[cc] * (hf - stats[cc]) * stats[128 + cc] + beta[cc];
    out[j] = fmaxf(v, 0.f);
  }
  *(float4*)(out_x + idx * 8) = make_float4(out[0], out[1], out[2], out[3]);
  *(float4*)(out_x + idx * 8 + 4) = make_float4(out[4], out[5], out[6], out[7]);
}

extern "C" void kernel_launch(void* const* d_in, const int* in_sizes, int n_in,
                              void* d_out, int out_size, void* d_ws, size_t ws_size,
                              hipStream_t stream) {
  const float* x = (const float*)d_in[0];
  // d_in[1] = e : unused by the forward
  const int* edge_index = (const int*)d_in[2];
  const float* Wa = (const float*)d_in[3];
  const float* ba = (const float*)d_in[4];
  const float* Wb = (const float*)d_in[5];
  const float* bb = (const float*)d_in[6];
  const float* Wd = (const float*)d_in[7];
  const float* bd = (const float*)d_in[8];
  const float* We = (const float*)d_in[9];
  const float* be = (const float*)d_in[10];
  const float* gamma = (const float*)d_in[11];
  const float* beta = (const float*)d_in[12];

  const int* src = edge_index;            // edge_index[0]
  const int* dst = edge_index + N_EDGES;  // edge_index[1]

  // workspace layout (bytes), all 16B-aligned; total ~132.7 MB
  char* w = (char*)d_ws;
  ushort* wt      = (ushort*)(w);               // 131072
  float*  biasc   = (float*)(w + 131072);       // 2048
  ushort* abde    = (ushort*)(w + 133120);      // 102,400,000
  ushort* hbuf    = (ushort*)(w + 102533120);   // 25,600,000
  int*    cnt     = (int*)(w + 128133120);      // 400,000
  int*    row_ptr = (int*)(w + 128533120);      // 400,128
  int*    cursor  = (int*)(w + 128933248);      // 400,000
  int*    csr_eid = (int*)(w + 129333248);      // 1,280,000
  float*  partials= (float*)(w + 130613248);    // 2,097,152
  float*  stats   = (float*)(w + 132710400);    // 1024

  float* out_x = (float*)d_out;
  float* out_e = out_x + (size_t)N_NODES * DIM;

  hipMemsetAsync(cnt, 0, N_NODES * sizeof(int), stream);
  k_prep<<<256, 256, 0, stream>>>(Wa, ba, Wb, bb, Wd, bd, We, be, wt, biasc);
  k_gemm<<<1563, 256, 0, stream>>>(x, wt, biasc, abde);
  k_count<<<(N_EDGES + 255) / 256, 256, 0, stream>>>(dst, cnt);
  k_scan<<<1, 1024, 0, stream>>>(cnt, row_ptr, cursor);
  k_scatter<<<(N_EDGES + 255) / 256, 256, 0, stream>>>(dst, cursor, csr_eid);
  k_node<<<NODE_BLOCKS, 256, 0, stream>>>(abde, row_ptr, csr_eid, src, out_e, hbuf, partials);
  k_stats<<<1, 128, 0, stream>>>(partials, stats);
  k_final<<<6250, 256, 0, stream>>>(hbuf, gamma, beta, stats, out_x);
}

// Round 2
// 225.131 us; speedup vs baseline: 2.4424x; 2.4424x over previous
//
#include <hip/hip_runtime.h>
#include <hip/hip_bf16.h>
#include <stdint.h>

#define N_NODES 100000
#define N_EDGES 320000
#define DIM 128
#define AGG_EPS 1e-6f
#define BN_EPS 1e-5f
#define NODE_BLOCKS 2048
#define SCAN_BLOCKS 391  // ceil(100000/256)

typedef float f32x4 __attribute__((ext_vector_type(4)));
typedef __bf16 bf16x8 __attribute__((ext_vector_type(8)));

__device__ __forceinline__ uint32_t f2bf(float f) {
  union { float f; uint32_t u; } v; v.f = f;
  uint32_t u = v.u;
  return (u + 0x7fffu + ((u >> 16) & 1u)) >> 16;  // RNE
}
__device__ __forceinline__ float bf2f(uint32_t h) {
  union { uint32_t u; float f; } v; v.u = h << 16;
  return v.f;
}

// ---------------- K0: weights -> transposed combined bf16 [512][128] ----------------
__global__ __launch_bounds__(256) void k_prep(
    const float* __restrict__ Wa, const float* __restrict__ ba,
    const float* __restrict__ Wb, const float* __restrict__ bb,
    const float* __restrict__ Wd, const float* __restrict__ bd,
    const float* __restrict__ We, const float* __restrict__ be,
    ushort* __restrict__ wt, float* __restrict__ biasc) {
  int t = blockIdx.x * 256 + threadIdx.x;  // 65536 = 512*128
  int n = t >> 7, k = t & 127;
  int sel = n >> 7, j = n & 127;
  const float* W = (sel == 0) ? Wa : (sel == 1) ? Wb : (sel == 2) ? Wd : We;
  wt[n * 128 + k] = (ushort)f2bf(W[k * 128 + j]);  // Wt[n][k] = W[k][n]
  if (t < 512) {
    int s2 = t >> 7;
    const float* b = (s2 == 0) ? ba : (s2 == 1) ? bb : (s2 == 2) ? bd : be;
    biasc[t] = b[t & 127];
  }
}

// ---------------- K1: ABDE[100000][512] bf16 = bf16(x) @ Wc + bias ----------------
__global__ __launch_bounds__(256) void k_gemm(
    const float* __restrict__ x, const ushort* __restrict__ wt,
    const float* __restrict__ biasc, ushort* __restrict__ abde) {
  __shared__ ushort As[64 * 128];
  __shared__ ushort Bs[64 * 128];
  const int tid = threadIdx.x;
  const int m0 = blockIdx.x * 64;

#pragma unroll
  for (int i = 0; i < 4; ++i) {
    int qid = tid + 256 * i;
    int row = qid >> 4, q = qid & 15;
    int gr = m0 + row;
    uint4 pk = make_uint4(0u, 0u, 0u, 0u);
    if (gr < N_NODES) {
      const float* s = x + gr * 128 + q * 8;
      float4 f0 = *(const float4*)(s);
      float4 f1 = *(const float4*)(s + 4);
      pk.x = f2bf(f0.x) | (f2bf(f0.y) << 16);
      pk.y = f2bf(f0.z) | (f2bf(f0.w) << 16);
      pk.z = f2bf(f1.x) | (f2bf(f1.y) << 16);
      pk.w = f2bf(f1.z) | (f2bf(f1.w) << 16);
    }
    int byte = (row * 256 + q * 16) ^ ((row & 7) << 4);
    *(uint4*)((char*)As + byte) = pk;
  }
  __syncthreads();

  const int w = tid >> 6, lane = tid & 63;
  const int r = lane & 15, g = lane >> 4;
  const int arow = w * 16 + r;

  bf16x8 afrag[4];
#pragma unroll
  for (int kk = 0; kk < 4; ++kk) {
    int ab = (arow * 256 + kk * 64 + g * 16) ^ ((arow & 7) << 4);
    afrag[kk] = *(const bf16x8*)((const char*)As + ab);
  }

  for (int nt = 0; nt < 8; ++nt) {
    const int n0 = nt * 64;
    __syncthreads();
#pragma unroll
    for (int i = 0; i < 4; ++i) {
      int qid = tid + 256 * i;
      int row = qid >> 4, q = qid & 15;
      uint4 v = *(const uint4*)(wt + (n0 + row) * 128 + q * 8);
      int byte = (row * 256 + q * 16) ^ ((row & 7) << 4);
      *(uint4*)((char*)Bs + byte) = v;
    }
    __syncthreads();

    f32x4 acc[4] = {{0.f,0.f,0.f,0.f},{0.f,0.f,0.f,0.f},{0.f,0.f,0.f,0.f},{0.f,0.f,0.f,0.f}};
#pragma unroll
    for (int kk = 0; kk < 4; ++kk) {
#pragma unroll
      for (int n = 0; n < 4; ++n) {
        int brow = n * 16 + r;
        int bb = (brow * 256 + kk * 64 + g * 16) ^ ((brow & 7) << 4);
        bf16x8 bv = *(const bf16x8*)((const char*)Bs + bb);
        acc[n] = __builtin_amdgcn_mfma_f32_16x16x32_bf16(afrag[kk], bv, acc[n], 0, 0, 0);
      }
    }
#pragma unroll
    for (int n = 0; n < 4; ++n) {
      int col = n0 + n * 16 + r;
      float bias = biasc[col];
#pragma unroll
      for (int q = 0; q < 4; ++q) {
        int row = m0 + w * 16 + g * 4 + q;
        if (row < N_NODES) abde[row * 512 + col] = (ushort)f2bf(acc[n][q] + bias);
      }
    }
  }
}

// ---------------- CSR build (hierarchical scan) ----------------
__global__ __launch_bounds__(256) void k_count(const int* __restrict__ dst,
                                               int* __restrict__ cnt) {
  int t = blockIdx.x * 256 + threadIdx.x;
  if (t < N_EDGES) atomicAdd(&cnt[dst[t]], 1);
}

// stage 1: per-block sums of cnt (391 blocks x 256)
__global__ __launch_bounds__(256) void k_bsum(const int* __restrict__ cnt,
                                              int* __restrict__ bsum) {
  __shared__ int lds[256];
  int t = threadIdx.x;
  int i = blockIdx.x * 256 + t;
  lds[t] = (i < N_NODES) ? cnt[i] : 0;
  __syncthreads();
#pragma unroll
  for (int off = 128; off > 0; off >>= 1) {
    if (t < off) lds[t] += lds[t + off];
    __syncthreads();
  }
  if (t == 0) bsum[blockIdx.x] = lds[0];
}

// stage 2: 1-block exclusive scan of 391 block sums (512-thread Hillis-Steele)
__global__ __launch_bounds__(512) void k_scanb(const int* __restrict__ bsum,
                                               int* __restrict__ boff,
                                               int* __restrict__ row_ptr) {
  __shared__ int lds[512];
  int t = threadIdx.x;
  int v = (t < SCAN_BLOCKS) ? bsum[t] : 0;
  lds[t] = v;
  __syncthreads();
  for (int off = 1; off < 512; off <<= 1) {
    int u = (t >= off) ? lds[t - off] : 0;
    __syncthreads();
    lds[t] += u;
    __syncthreads();
  }
  if (t < SCAN_BLOCKS) boff[t] = lds[t] - v;  // exclusive
  if (t == SCAN_BLOCKS - 1) row_ptr[N_NODES] = lds[t];
}

// stage 3: per-block exclusive scan + global offset -> row_ptr/cursor
__global__ __launch_bounds__(256) void k_scan3(const int* __restrict__ cnt,
                                               const int* __restrict__ boff,
                                               int* __restrict__ row_ptr,
                                               int* __restrict__ cursor) {
  __shared__ int lds[256];
  int t = threadIdx.x;
  int i = blockIdx.x * 256 + t;
  int v = (i < N_NODES) ? cnt[i] : 0;
  lds[t] = v;
  __syncthreads();
  for (int off = 1; off < 256; off <<= 1) {
    int u = (t >= off) ? lds[t - off] : 0;
    __syncthreads();
    lds[t] += u;
    __syncthreads();
  }
  if (i < N_NODES) {
    int ex = boff[blockIdx.x] + lds[t] - v;
    row_ptr[i] = ex;
    cursor[i] = ex;
  }
}

__global__ __launch_bounds__(256) void k_scatter(const int* __restrict__ dst,
                                                 int* __restrict__ cursor,
                                                 int* __restrict__ csr_eid) {
  int t = blockIdx.x * 256 + threadIdx.x;
  if (t < N_EDGES) {
    int d = dst[t];
    int pos = atomicAdd(&cursor[d], 1);
    csr_eid[pos] = t;
  }
}

// ---------------- K5: wave-per-node fused edge+aggregate+h+BN-partials ----------------
__global__ __launch_bounds__(256) void k_node(
    const ushort* __restrict__ abde, const int* __restrict__ row_ptr,
    const int* __restrict__ csr_eid, const int* __restrict__ esrc,
    float* __restrict__ out_e, ushort* __restrict__ h,
    float* __restrict__ partials) {
  const int tid = threadIdx.x;
  const int lane = tid & 63;
  const int wid = (blockIdx.x << 2) | (tid >> 6);
  const int nw = NODE_BLOCKS * 4;
  float s0 = 0.f, s1 = 0.f, q0 = 0.f, q1 = 0.f;
  for (int i = wid; i < N_NODES; i += nw) {
    uint32_t axu = *(const uint32_t*)(abde + i * 512 + 2 * lane);        // Ax
    uint32_t dxu = *(const uint32_t*)(abde + i * 512 + 256 + 2 * lane);  // Dx
    float ax0 = bf2f(axu & 0xffffu), ax1 = bf2f(axu >> 16);
    float dx0 = bf2f(dxu & 0xffffu), dx1 = bf2f(dxu >> 16);
    float n0 = 0.f, n1 = 0.f, d0 = 0.f, d1 = 0.f;
    int ke = row_ptr[i + 1];
    for (int k = row_ptr[i]; k < ke; ++k) {
      int eid = csr_eid[k];
      int src = esrc[eid];
      uint32_t exu = *(const uint32_t*)(abde + src * 512 + 384 + 2 * lane);  // Ex
      uint32_t bxu = *(const uint32_t*)(abde + src * 512 + 128 + 2 * lane);  // Bx
      float e0 = dx0 + bf2f(exu & 0xffffu);
      float e1 = dx1 + bf2f(exu >> 16);
      *(float2*)(out_e + (size_t)eid * 128 + 2 * lane) = make_float2(e0, e1);
      float sg0 = 1.f / (1.f + __expf(-e0));
      float sg1 = 1.f / (1.f + __expf(-e1));
      n0 += sg0 * bf2f(bxu & 0xffffu);
      n1 += sg1 * bf2f(bxu >> 16);
      d0 += sg0; d1 += sg1;
    }
    float h0 = ax0 + n0 / (d0 + AGG_EPS);
    float h1 = ax1 + n1 / (d1 + AGG_EPS);
    *(uint32_t*)(h + i * 128 + 2 * lane) = f2bf(h0) | (f2bf(h1) << 16);
    s0 += h0; s1 += h1; q0 += h0 * h0; q1 += h1 * h1;
  }
  __shared__ float red[256 * 4];
  red[tid] = s0; red[256 + tid] = s1; red[512 + tid] = q0; red[768 + tid] = q1;
  __syncthreads();
  if (tid < 64) {
    float vs0 = red[tid] + red[tid + 64] + red[tid + 128] + red[tid + 192];
    float vs1 = red[256 + tid] + red[256 + tid + 64] + red[256 + tid + 128] + red[256 + tid + 192];
    float vq0 = red[512 + tid] + red[512 + tid + 64] + red[512 + tid + 128] + red[512 + tid + 192];
    float vq1 = red[768 + tid] + red[768 + tid + 64] + red[768 + tid + 128] + red[768 + tid + 192];
    float* p = partials + blockIdx.x * 256;
    p[2 * tid] = vs0;
    p[2 * tid + 1] = vs1;
    p[128 + 2 * tid] = vq0;
    p[128 + 2 * tid + 1] = vq1;
  }
}

// ---------------- K6a: partials 2048 -> 64 (coalesced) ----------------
__global__ __launch_bounds__(256) void k_stats1(const float* __restrict__ partials,
                                                float* __restrict__ out2) {
  int t = threadIdx.x, b = blockIdx.x;  // 64 blocks
  float s = 0.f;
#pragma unroll
  for (int j = 0; j < 32; ++j) s += partials[(b * 32 + j) * 256 + t];
  out2[b * 256 + t] = s;
}

// ---------------- K6b: 64 -> stats ----------------
__global__ __launch_bounds__(128) void k_stats2(const float* __restrict__ out2,
                                                float* __restrict__ stats) {
  int c = threadIdx.x;
  float s = 0.f, q = 0.f;
#pragma unroll
  for (int b = 0; b < 64; ++b) {
    s += out2[b * 256 + c];
    q += out2[b * 256 + 128 + c];
  }
  float mean = s * (1.f / (float)N_NODES);
  float var = q * (1.f / (float)N_NODES) - mean * mean;
  stats[c] = mean;
  stats[128 + c] = rsqrtf(var + BN_EPS);
}

// ---------------- K7: normalize + ReLU ----------------
__global__ __launch_bounds__(256) void k_final(const ushort* __restrict__ h,
    const float* __restrict__ gamma, const float* __restrict__ beta,
    const float* __restrict__ stats, float* __restrict__ out_x) {
  int idx = blockIdx.x * 256 + threadIdx.x;  // 1,600,000 units of 8 elems
  int c = (idx & 15) * 8;
  uint4 hv = *(const uint4*)(h + idx * 8);
  uint32_t hw[4] = {hv.x, hv.y, hv.z, hv.w};
  float out[8];
#pragma unroll
  for (int j = 0; j < 8; ++j) {
    uint32_t u = (j & 1) ? (hw[j >> 1] >> 16) : (hw[j >> 1] & 0xffffu);
    float hf = bf2f(u);
    int cc = c + j;
    float v = gamma[cc] * (hf - stats[cc]) * stats[128 + cc] + beta[cc];
    out[j] = fmaxf(v, 0.f);
  }
  *(float4*)(out_x + idx * 8) = make_float4(out[0], out[1], out[2], out[3]);
  *(float4*)(out_x + idx * 8 + 4) = make_float4(out[4], out[5], out[6], out[7]);
}

extern "C" void kernel_launch(void* const* d_in, const int* in_sizes, int n_in,
                              void* d_out, int out_size, void* d_ws, size_t ws_size,
                              hipStream_t stream) {
  const float* x = (const float*)d_in[0];
  const int* edge_index = (const int*)d_in[2];
  const float* Wa = (const float*)d_in[3];
  const float* ba = (const float*)d_in[4];
  const float* Wb = (const float*)d_in[5];
  const float* bb = (const float*)d_in[6];
  const float* Wd = (const float*)d_in[7];
  const float* bd = (const float*)d_in[8];
  const float* We = (const float*)d_in[9];
  const float* be = (const float*)d_in[10];
  const float* gamma = (const float*)d_in[11];
  const float* beta = (const float*)d_in[12];

  const int* src = edge_index;            // edge_index[0]
  const int* dst = edge_index + N_EDGES;  // edge_index[1]

  // workspace layout (bytes), all 16B-aligned; total ~132.7 MB (unchanged from R1)
  char* w = (char*)d_ws;
  ushort* wt      = (ushort*)(w);               // 131072
  float*  biasc   = (float*)(w + 131072);       // 2048
  ushort* abde    = (ushort*)(w + 133120);      // 102,400,000
  ushort* hbuf    = (ushort*)(w + 102533120);   // 25,600,000
  int*    cnt     = (int*)(w + 128133120);      // 400,000
  int*    row_ptr = (int*)(w + 128533120);      // 400,128
  int*    cursor  = (int*)(w + 128933248);      // 400,000
  int*    csr_eid = (int*)(w + 129333248);      // 1,280,000
  float*  partials= (float*)(w + 130613248);    // 2,097,152
  float*  stats   = (float*)(w + 132710400);    // 1024

  // overlays (no ws growth):
  //  - bsum/boff live in partials region (partials written only later by k_node)
  //  - out2 reuses cnt region (cnt dead after k_scan3; out2 fully overwritten)
  int*   bsum = (int*)partials;
  int*   boff = (int*)(partials + 512);
  float* out2 = (float*)cnt;  // 64*256*4 = 65536 <= 400000

  float* out_x = (float*)d_out;
  float* out_e = out_x + (size_t)N_NODES * DIM;

  hipMemsetAsync(cnt, 0, N_NODES * sizeof(int), stream);
  k_prep<<<256, 256, 0, stream>>>(Wa, ba, Wb, bb, Wd, bd, We, be, wt, biasc);
  k_gemm<<<1563, 256, 0, stream>>>(x, wt, biasc, abde);
  k_count<<<(N_EDGES + 255) / 256, 256, 0, stream>>>(dst, cnt);
  k_bsum<<<SCAN_BLOCKS, 256, 0, stream>>>(cnt, bsum);
  k_scanb<<<1, 512, 0, stream>>>(bsum, boff, row_ptr);
  k_scan3<<<SCAN_BLOCKS, 256, 0, stream>>>(cnt, boff, row_ptr, cursor);
  k_scatter<<<(N_EDGES + 255) / 256, 256, 0, stream>>>(dst, cursor, csr_eid);
  k_node<<<NODE_BLOCKS, 256, 0, stream>>>(abde, row_ptr, csr_eid, src, out_e, hbuf, partials);
  k_stats1<<<64, 256, 0, stream>>>(partials, out2);
  k_stats2<<<1, 128, 0, stream>>>(out2, stats);
  k_final<<<6250, 256, 0, stream>>>(hbuf, gamma, beta, stats, out_x);
}

// Round 4
// 224.485 us; speedup vs baseline: 2.4495x; 1.0029x over previous
//
#include <hip/hip_runtime.h>
#include <hip/hip_bf16.h>
#include <stdint.h>

#define N_NODES 100000
#define N_EDGES 320000
#define DIM 128
#define AGG_EPS 1e-6f
#define BN_EPS 1e-5f
#define NODE_BLOCKS 2048
#define SCAN_BLOCKS 391  // ceil(100000/256)

typedef float f32x4 __attribute__((ext_vector_type(4)));
typedef __bf16 bf16x8 __attribute__((ext_vector_type(8)));

__device__ __forceinline__ uint32_t f2bf(float f) {
  union { float f; uint32_t u; } v; v.f = f;
  uint32_t u = v.u;
  return (u + 0x7fffu + ((u >> 16) & 1u)) >> 16;  // RNE
}
__device__ __forceinline__ float bf2f(uint32_t h) {
  union { uint32_t u; float f; } v; v.u = h << 16;
  return v.f;
}

// ---------------- K-1: zero cnt. 100,000 ints = 25,000 uint4 (R3 bug: only covered 6,250) ----
__global__ __launch_bounds__(256) void k_zero(uint4* __restrict__ p) {
  int t = blockIdx.x * 256 + threadIdx.x;
  if (t < 25000) p[t] = make_uint4(0u, 0u, 0u, 0u);
}

// ---------------- K0: weights -> transposed combined bf16 [512][128] ----------------
__global__ __launch_bounds__(256) void k_prep(
    const float* __restrict__ Wa, const float* __restrict__ ba,
    const float* __restrict__ Wb, const float* __restrict__ bb,
    const float* __restrict__ Wd, const float* __restrict__ bd,
    const float* __restrict__ We, const float* __restrict__ be,
    ushort* __restrict__ wt, float* __restrict__ biasc) {
  int t = blockIdx.x * 256 + threadIdx.x;  // 65536 = 512*128
  int n = t >> 7, k = t & 127;
  int sel = n >> 7, j = n & 127;
  const float* W = (sel == 0) ? Wa : (sel == 1) ? Wb : (sel == 2) ? Wd : We;
  wt[n * 128 + k] = (ushort)f2bf(W[k * 128 + j]);  // Wt[n][k] = W[k][n]
  if (t < 512) {
    int s2 = t >> 7;
    const float* b = (s2 == 0) ? ba : (s2 == 1) ? bb : (s2 == 2) ? bd : be;
    biasc[t] = b[t & 127];
  }
}

// ---------------- K1: ABDE[100000][512] bf16 = bf16(x) @ Wc + bias ----------------
__global__ __launch_bounds__(256) void k_gemm(
    const float* __restrict__ x, const ushort* __restrict__ wt,
    const float* __restrict__ biasc, ushort* __restrict__ abde) {
  __shared__ ushort As[64 * 128];
  __shared__ ushort Bs[64 * 128];
  const int tid = threadIdx.x;
  const int m0 = blockIdx.x * 64;

#pragma unroll
  for (int i = 0; i < 4; ++i) {
    int qid = tid + 256 * i;
    int row = qid >> 4, q = qid & 15;
    int gr = m0 + row;
    uint4 pk = make_uint4(0u, 0u, 0u, 0u);
    if (gr < N_NODES) {
      const float* s = x + gr * 128 + q * 8;
      float4 f0 = *(const float4*)(s);
      float4 f1 = *(const float4*)(s + 4);
      pk.x = f2bf(f0.x) | (f2bf(f0.y) << 16);
      pk.y = f2bf(f0.z) | (f2bf(f0.w) << 16);
      pk.z = f2bf(f1.x) | (f2bf(f1.y) << 16);
      pk.w = f2bf(f1.z) | (f2bf(f1.w) << 16);
    }
    int byte = (row * 256 + q * 16) ^ ((row & 7) << 4);
    *(uint4*)((char*)As + byte) = pk;
  }
  __syncthreads();

  const int w = tid >> 6, lane = tid & 63;
  const int r = lane & 15, g = lane >> 4;
  const int arow = w * 16 + r;

  bf16x8 afrag[4];
#pragma unroll
  for (int kk = 0; kk < 4; ++kk) {
    int ab = (arow * 256 + kk * 64 + g * 16) ^ ((arow & 7) << 4);
    afrag[kk] = *(const bf16x8*)((const char*)As + ab);
  }

  for (int nt = 0; nt < 8; ++nt) {
    const int n0 = nt * 64;
    __syncthreads();
#pragma unroll
    for (int i = 0; i < 4; ++i) {
      int qid = tid + 256 * i;
      int row = qid >> 4, q = qid & 15;
      uint4 v = *(const uint4*)(wt + (n0 + row) * 128 + q * 8);
      int byte = (row * 256 + q * 16) ^ ((row & 7) << 4);
      *(uint4*)((char*)Bs + byte) = v;
    }
    __syncthreads();

    f32x4 acc[4] = {{0.f,0.f,0.f,0.f},{0.f,0.f,0.f,0.f},{0.f,0.f,0.f,0.f},{0.f,0.f,0.f,0.f}};
#pragma unroll
    for (int kk = 0; kk < 4; ++kk) {
#pragma unroll
      for (int n = 0; n < 4; ++n) {
        int brow = n * 16 + r;
        int bb = (brow * 256 + kk * 64 + g * 16) ^ ((brow & 7) << 4);
        bf16x8 bv = *(const bf16x8*)((const char*)Bs + bb);
        acc[n] = __builtin_amdgcn_mfma_f32_16x16x32_bf16(afrag[kk], bv, acc[n], 0, 0, 0);
      }
    }
#pragma unroll
    for (int n = 0; n < 4; ++n) {
      int col = n0 + n * 16 + r;
      float bias = biasc[col];
#pragma unroll
      for (int q = 0; q < 4; ++q) {
        int row = m0 + w * 16 + g * 4 + q;
        if (row < N_NODES) abde[row * 512 + col] = (ushort)f2bf(acc[n][q] + bias);
      }
    }
  }
}

// ---------------- CSR build (hierarchical scan) ----------------
__global__ __launch_bounds__(256) void k_count(const int* __restrict__ dst,
                                               int* __restrict__ cnt) {
  int t = blockIdx.x * 256 + threadIdx.x;
  if (t < N_EDGES) atomicAdd(&cnt[dst[t]], 1);
}

// stage 1: per-block sums of cnt (391 blocks x 256)
__global__ __launch_bounds__(256) void k_bsum(const int* __restrict__ cnt,
                                              int* __restrict__ bsum) {
  __shared__ int lds[256];
  int t = threadIdx.x;
  int i = blockIdx.x * 256 + t;
  lds[t] = (i < N_NODES) ? cnt[i] : 0;
  __syncthreads();
#pragma unroll
  for (int off = 128; off > 0; off >>= 1) {
    if (t < off) lds[t] += lds[t + off];
    __syncthreads();
  }
  if (t == 0) bsum[blockIdx.x] = lds[0];
}

// stage 2: 1-block exclusive scan of 391 block sums (512-thread Hillis-Steele)
__global__ __launch_bounds__(512) void k_scanb(const int* __restrict__ bsum,
                                               int* __restrict__ boff,
                                               int* __restrict__ row_ptr) {
  __shared__ int lds[512];
  int t = threadIdx.x;
  int v = (t < SCAN_BLOCKS) ? bsum[t] : 0;
  lds[t] = v;
  __syncthreads();
  for (int off = 1; off < 512; off <<= 1) {
    int u = (t >= off) ? lds[t - off] : 0;
    __syncthreads();
    lds[t] += u;
    __syncthreads();
  }
  if (t < SCAN_BLOCKS) boff[t] = lds[t] - v;  // exclusive
  if (t == SCAN_BLOCKS - 1) row_ptr[N_NODES] = lds[t];
}

// stage 3: per-block exclusive scan + global offset -> row_ptr/cursor
__global__ __launch_bounds__(256) void k_scan3(const int* __restrict__ cnt,
                                               const int* __restrict__ boff,
                                               int* __restrict__ row_ptr,
                                               int* __restrict__ cursor) {
  __shared__ int lds[256];
  int t = threadIdx.x;
  int i = blockIdx.x * 256 + t;
  int v = (i < N_NODES) ? cnt[i] : 0;
  lds[t] = v;
  __syncthreads();
  for (int off = 1; off < 256; off <<= 1) {
    int u = (t >= off) ? lds[t - off] : 0;
    __syncthreads();
    lds[t] += u;
    __syncthreads();
  }
  if (i < N_NODES) {
    int ex = boff[blockIdx.x] + lds[t] - v;
    row_ptr[i] = ex;
    cursor[i] = ex;
  }
}

__global__ __launch_bounds__(256) void k_scatter(const int* __restrict__ dst,
                                                 int* __restrict__ cursor,
                                                 int* __restrict__ csr_eid) {
  int t = blockIdx.x * 256 + threadIdx.x;
  if (t < N_EDGES) {
    int d = dst[t];
    int pos = atomicAdd(&cursor[d], 1);
    csr_eid[pos] = t;
  }
}

// ---------------- K5: wave-per-node fused edge+aggregate+h+BN-partials ----------------
__global__ __launch_bounds__(256) void k_node(
    const ushort* __restrict__ abde, const int* __restrict__ row_ptr,
    const int* __restrict__ csr_eid, const int* __restrict__ esrc,
    float* __restrict__ out_e, ushort* __restrict__ h,
    float* __restrict__ partials) {
  const int tid = threadIdx.x;
  const int lane = tid & 63;
  const int wid = (blockIdx.x << 2) | (tid >> 6);
  const int nw = NODE_BLOCKS * 4;
  float s0 = 0.f, s1 = 0.f, q0 = 0.f, q1 = 0.f;
  for (int i = wid; i < N_NODES; i += nw) {
    uint32_t axu = *(const uint32_t*)(abde + i * 512 + 2 * lane);        // Ax
    uint32_t dxu = *(const uint32_t*)(abde + i * 512 + 256 + 2 * lane);  // Dx
    float ax0 = bf2f(axu & 0xffffu), ax1 = bf2f(axu >> 16);
    float dx0 = bf2f(dxu & 0xffffu), dx1 = bf2f(dxu >> 16);
    float n0 = 0.f, n1 = 0.f, d0 = 0.f, d1 = 0.f;
    int ke = row_ptr[i + 1];
    for (int k = row_ptr[i]; k < ke; ++k) {
      int eid = csr_eid[k];
      int src = esrc[eid];
      uint32_t exu = *(const uint32_t*)(abde + src * 512 + 384 + 2 * lane);  // Ex
      uint32_t bxu = *(const uint32_t*)(abde + src * 512 + 128 + 2 * lane);  // Bx
      float e0 = dx0 + bf2f(exu & 0xffffu);
      float e1 = dx1 + bf2f(exu >> 16);
      *(float2*)(out_e + (size_t)eid * 128 + 2 * lane) = make_float2(e0, e1);
      float sg0 = 1.f / (1.f + __expf(-e0));
      float sg1 = 1.f / (1.f + __expf(-e1));
      n0 += sg0 * bf2f(bxu & 0xffffu);
      n1 += sg1 * bf2f(bxu >> 16);
      d0 += sg0; d1 += sg1;
    }
    float h0 = ax0 + n0 / (d0 + AGG_EPS);
    float h1 = ax1 + n1 / (d1 + AGG_EPS);
    *(uint32_t*)(h + i * 128 + 2 * lane) = f2bf(h0) | (f2bf(h1) << 16);
    s0 += h0; s1 += h1; q0 += h0 * h0; q1 += h1 * h1;
  }
  __shared__ float red[256 * 4];
  red[tid] = s0; red[256 + tid] = s1; red[512 + tid] = q0; red[768 + tid] = q1;
  __syncthreads();
  if (tid < 64) {
    float vs0 = red[tid] + red[tid + 64] + red[tid + 128] + red[tid + 192];
    float vs1 = red[256 + tid] + red[256 + tid + 64] + red[256 + tid + 128] + red[256 + tid + 192];
    float vq0 = red[512 + tid] + red[512 + tid + 64] + red[512 + tid + 128] + red[512 + tid + 192];
    float vq1 = red[768 + tid] + red[768 + tid + 64] + red[768 + tid + 128] + red[768 + tid + 192];
    float* p = partials + blockIdx.x * 256;
    p[2 * tid] = vs0;
    p[2 * tid + 1] = vs1;
    p[128 + 2 * tid] = vq0;
    p[128 + 2 * tid + 1] = vq1;
  }
}

// ---------------- K6a: partials 2048 -> 64 (coalesced) ----------------
__global__ __launch_bounds__(256) void k_stats1(const float* __restrict__ partials,
                                                float* __restrict__ out2) {
  int t = threadIdx.x, b = blockIdx.x;  // 64 blocks
  float s = 0.f;
#pragma unroll
  for (int j = 0; j < 32; ++j) s += partials[(b * 32 + j) * 256 + t];
  out2[b * 256 + t] = s;
}

// ---------------- K6b: 64 -> stats ----------------
__global__ __launch_bounds__(128) void k_stats2(const float* __restrict__ out2,
                                                float* __restrict__ stats) {
  int c = threadIdx.x;
  float s = 0.f, q = 0.f;
#pragma unroll
  for (int b = 0; b < 64; ++b) {
    s += out2[b * 256 + c];
    q += out2[b * 256 + 128 + c];
  }
  float mean = s * (1.f / (float)N_NODES);
  float var = q * (1.f / (float)N_NODES) - mean * mean;
  stats[c] = mean;
  stats[128 + c] = rsqrtf(var + BN_EPS);
}

// ---------------- K7: normalize + ReLU ----------------
__global__ __launch_bounds__(256) void k_final(const ushort* __restrict__ h,
    const float* __restrict__ gamma, const float* __restrict__ beta,
    const float* __restrict__ stats, float* __restrict__ out_x) {
  int idx = blockIdx.x * 256 + threadIdx.x;  // 1,600,000 units of 8 elems
  int c = (idx & 15) * 8;
  uint4 hv = *(const uint4*)(h + idx * 8);
  uint32_t hw[4] = {hv.x, hv.y, hv.z, hv.w};
  float out[8];
#pragma unroll
  for (int j = 0; j < 8; ++j) {
    uint32_t u = (j & 1) ? (hw[j >> 1] >> 16) : (hw[j >> 1] & 0xffffu);
    float hf = bf2f(u);
    int cc = c + j;
    float v = gamma[cc] * (hf - stats[cc]) * stats[128 + cc] + beta[cc];
    out[j] = fmaxf(v, 0.f);
  }
  *(float4*)(out_x + idx * 8) = make_float4(out[0], out[1], out[2], out[3]);
  *(float4*)(out_x + idx * 8 + 4) = make_float4(out[4], out[5], out[6], out[7]);
}

extern "C" void kernel_launch(void* const* d_in, const int* in_sizes, int n_in,
                              void* d_out, int out_size, void* d_ws, size_t ws_size,
                              hipStream_t stream) {
  const float* x = (const float*)d_in[0];
  const int* edge_index = (const int*)d_in[2];
  const float* Wa = (const float*)d_in[3];
  const float* ba = (const float*)d_in[4];
  const float* Wb = (const float*)d_in[5];
  const float* bb = (const float*)d_in[6];
  const float* Wd = (const float*)d_in[7];
  const float* bd = (const float*)d_in[8];
  const float* We = (const float*)d_in[9];
  const float* be = (const float*)d_in[10];
  const float* gamma = (const float*)d_in[11];
  const float* beta = (const float*)d_in[12];

  const int* src = edge_index;            // edge_index[0]
  const int* dst = edge_index + N_EDGES;  // edge_index[1]

  // workspace layout (bytes), all 16B-aligned; total ~132.7 MB
  char* w = (char*)d_ws;
  ushort* wt      = (ushort*)(w);               // 131072
  float*  biasc   = (float*)(w + 131072);       // 2048
  ushort* abde    = (ushort*)(w + 133120);      // 102,400,000
  ushort* hbuf    = (ushort*)(w + 102533120);   // 25,600,000
  int*    cnt     = (int*)(w + 128133120);      // 400,000
  int*    row_ptr = (int*)(w + 128533120);      // 400,128
  int*    cursor  = (int*)(w + 128933248);      // 400,000
  int*    csr_eid = (int*)(w + 129333248);      // 1,280,000
  float*  partials= (float*)(w + 130613248);    // 2,097,152
  float*  stats   = (float*)(w + 132710400);    // 1024

  // overlays (no ws growth):
  int*   bsum = (int*)partials;
  int*   boff = (int*)(partials + 512);
  float* out2 = (float*)cnt;  // dead after k_scan3; fully overwritten by k_stats1

  float* out_x = (float*)d_out;
  float* out_e = out_x + (size_t)N_NODES * DIM;

  k_zero<<<98, 256, 0, stream>>>((uint4*)cnt);  // 25,000 uint4 = 400,000 B
  k_prep<<<256, 256, 0, stream>>>(Wa, ba, Wb, bb, Wd, bd, We, be, wt, biasc);
  k_gemm<<<1563, 256, 0, stream>>>(x, wt, biasc, abde);
  k_count<<<(N_EDGES + 255) / 256, 256, 0, stream>>>(dst, cnt);
  k_bsum<<<SCAN_BLOCKS, 256, 0, stream>>>(cnt, bsum);
  k_scanb<<<1, 512, 0, stream>>>(bsum, boff, row_ptr);
  k_scan3<<<SCAN_BLOCKS, 256, 0, stream>>>(cnt, boff, row_ptr, cursor);
  k_scatter<<<(N_EDGES + 255) / 256, 256, 0, stream>>>(dst, cursor, csr_eid);
  k_node<<<NODE_BLOCKS, 256, 0, stream>>>(abde, row_ptr, csr_eid, src, out_e, hbuf, partials);
  k_stats1<<<64, 256, 0, stream>>>(partials, out2);
  k_stats2<<<1, 128, 0, stream>>>(out2, stats);
  k_final<<<6250, 256, 0, stream>>>(hbuf, gamma, beta, stats, out_x);
}

// Round 5
// 212.591 us; speedup vs baseline: 2.5865x; 1.0559x over previous
//
#include <hip/hip_runtime.h>
#include <hip/hip_bf16.h>
#include <stdint.h>

#define N_NODES 100000
#define N_EDGES 320000
#define DIM 128
#define AGG_EPS 1e-6f
#define BN_EPS 1e-5f
#define NODE_BLOCKS 2048
#define SCAN_BLOCKS 391  // ceil(100000/256)

typedef float f32x4 __attribute__((ext_vector_type(4)));
typedef __bf16 bf16x8 __attribute__((ext_vector_type(8)));

__device__ __forceinline__ uint32_t f2bf(float f) {
  union { float f; uint32_t u; } v; v.f = f;
  uint32_t u = v.u;
  return (u + 0x7fffu + ((u >> 16) & 1u)) >> 16;  // RNE
}
__device__ __forceinline__ float bf2f(uint32_t h) {
  union { uint32_t u; float f; } v; v.u = h << 16;
  return v.f;
}

// ---------------- K0: weights -> transposed combined bf16 [512][128]; also zeroes cnt ----
__global__ __launch_bounds__(256) void k_prep(
    const float* __restrict__ Wa, const float* __restrict__ ba,
    const float* __restrict__ Wb, const float* __restrict__ bb,
    const float* __restrict__ Wd, const float* __restrict__ bd,
    const float* __restrict__ We, const float* __restrict__ be,
    ushort* __restrict__ wt, float* __restrict__ biasc,
    uint4* __restrict__ cnt_zero) {
  int t = blockIdx.x * 256 + threadIdx.x;  // 65536 = 512*128
  if (t < 25000) cnt_zero[t] = make_uint4(0u, 0u, 0u, 0u);  // 100,000 ints
  int n = t >> 7, k = t & 127;
  int sel = n >> 7, j = n & 127;
  const float* W = (sel == 0) ? Wa : (sel == 1) ? Wb : (sel == 2) ? Wd : We;
  wt[n * 128 + k] = (ushort)f2bf(W[k * 128 + j]);  // Wt[n][k] = W[k][n]
  if (t < 512) {
    int s2 = t >> 7;
    const float* b = (s2 == 0) ? ba : (s2 == 1) ? bb : (s2 == 2) ? bd : be;
    biasc[t] = b[t & 127];
  }
}

// ---------------- K1: ABDE[100000][512] bf16 = bf16(x) @ Wc + bias ----------------
__global__ __launch_bounds__(256) void k_gemm(
    const float* __restrict__ x, const ushort* __restrict__ wt,
    const float* __restrict__ biasc, ushort* __restrict__ abde) {
  __shared__ ushort As[64 * 128];
  __shared__ ushort Bs[64 * 128];
  const int tid = threadIdx.x;
  const int m0 = blockIdx.x * 64;

#pragma unroll
  for (int i = 0; i < 4; ++i) {
    int qid = tid + 256 * i;
    int row = qid >> 4, q = qid & 15;
    int gr = m0 + row;
    uint4 pk = make_uint4(0u, 0u, 0u, 0u);
    if (gr < N_NODES) {
      const float* s = x + gr * 128 + q * 8;
      float4 f0 = *(const float4*)(s);
      float4 f1 = *(const float4*)(s + 4);
      pk.x = f2bf(f0.x) | (f2bf(f0.y) << 16);
      pk.y = f2bf(f0.z) | (f2bf(f0.w) << 16);
      pk.z = f2bf(f1.x) | (f2bf(f1.y) << 16);
      pk.w = f2bf(f1.z) | (f2bf(f1.w) << 16);
    }
    int byte = (row * 256 + q * 16) ^ ((row & 7) << 4);
    *(uint4*)((char*)As + byte) = pk;
  }
  __syncthreads();

  const int w = tid >> 6, lane = tid & 63;
  const int r = lane & 15, g = lane >> 4;
  const int arow = w * 16 + r;

  bf16x8 afrag[4];
#pragma unroll
  for (int kk = 0; kk < 4; ++kk) {
    int ab = (arow * 256 + kk * 64 + g * 16) ^ ((arow & 7) << 4);
    afrag[kk] = *(const bf16x8*)((const char*)As + ab);
  }

  for (int nt = 0; nt < 8; ++nt) {
    const int n0 = nt * 64;
    __syncthreads();
#pragma unroll
    for (int i = 0; i < 4; ++i) {
      int qid = tid + 256 * i;
      int row = qid >> 4, q = qid & 15;
      uint4 v = *(const uint4*)(wt + (n0 + row) * 128 + q * 8);
      int byte = (row * 256 + q * 16) ^ ((row & 7) << 4);
      *(uint4*)((char*)Bs + byte) = v;
    }
    __syncthreads();

    f32x4 acc[4] = {{0.f,0.f,0.f,0.f},{0.f,0.f,0.f,0.f},{0.f,0.f,0.f,0.f},{0.f,0.f,0.f,0.f}};
#pragma unroll
    for (int kk = 0; kk < 4; ++kk) {
#pragma unroll
      for (int n = 0; n < 4; ++n) {
        int brow = n * 16 + r;
        int bb = (brow * 256 + kk * 64 + g * 16) ^ ((brow & 7) << 4);
        bf16x8 bv = *(const bf16x8*)((const char*)Bs + bb);
        acc[n] = __builtin_amdgcn_mfma_f32_16x16x32_bf16(afrag[kk], bv, acc[n], 0, 0, 0);
      }
    }
#pragma unroll
    for (int n = 0; n < 4; ++n) {
      int col = n0 + n * 16 + r;
      float bias = biasc[col];
#pragma unroll
      for (int q = 0; q < 4; ++q) {
        int row = m0 + w * 16 + g * 4 + q;
        if (row < N_NODES) abde[row * 512 + col] = (ushort)f2bf(acc[n][q] + bias);
      }
    }
  }
}

// ---------------- CSR build (hierarchical scan) ----------------
__global__ __launch_bounds__(256) void k_count(const int* __restrict__ dst,
                                               int* __restrict__ cnt) {
  int t = blockIdx.x * 256 + threadIdx.x;
  if (t < N_EDGES) atomicAdd(&cnt[dst[t]], 1);
}

__global__ __launch_bounds__(256) void k_bsum(const int* __restrict__ cnt,
                                              int* __restrict__ bsum) {
  __shared__ int lds[256];
  int t = threadIdx.x;
  int i = blockIdx.x * 256 + t;
  lds[t] = (i < N_NODES) ? cnt[i] : 0;
  __syncthreads();
#pragma unroll
  for (int off = 128; off > 0; off >>= 1) {
    if (t < off) lds[t] += lds[t + off];
    __syncthreads();
  }
  if (t == 0) bsum[blockIdx.x] = lds[0];
}

__global__ __launch_bounds__(512) void k_scanb(const int* __restrict__ bsum,
                                               int* __restrict__ boff,
                                               int* __restrict__ row_ptr) {
  __shared__ int lds[512];
  int t = threadIdx.x;
  int v = (t < SCAN_BLOCKS) ? bsum[t] : 0;
  lds[t] = v;
  __syncthreads();
  for (int off = 1; off < 512; off <<= 1) {
    int u = (t >= off) ? lds[t - off] : 0;
    __syncthreads();
    lds[t] += u;
    __syncthreads();
  }
  if (t < SCAN_BLOCKS) boff[t] = lds[t] - v;  // exclusive
  if (t == SCAN_BLOCKS - 1) row_ptr[N_NODES] = lds[t];
}

__global__ __launch_bounds__(256) void k_scan3(const int* __restrict__ cnt,
                                               const int* __restrict__ boff,
                                               int* __restrict__ row_ptr,
                                               int* __restrict__ cursor) {
  __shared__ int lds[256];
  int t = threadIdx.x;
  int i = blockIdx.x * 256 + t;
  int v = (i < N_NODES) ? cnt[i] : 0;
  lds[t] = v;
  __syncthreads();
  for (int off = 1; off < 256; off <<= 1) {
    int u = (t >= off) ? lds[t - off] : 0;
    __syncthreads();
    lds[t] += u;
    __syncthreads();
  }
  if (i < N_NODES) {
    int ex = boff[blockIdx.x] + lds[t] - v;
    row_ptr[i] = ex;
    cursor[i] = ex;
  }
}

__global__ __launch_bounds__(256) void k_scatter(const int* __restrict__ dst,
                                                 int* __restrict__ cursor,
                                                 int* __restrict__ csr_eid) {
  int t = blockIdx.x * 256 + threadIdx.x;
  if (t < N_EDGES) {
    int d = dst[t];
    int pos = atomicAdd(&cursor[d], 1);
    csr_eid[pos] = t;
  }
}

// ---------------- K5: wave-per-node fused edge+aggregate+h+BN-partials -------------
// v2: lane-parallel index fetch (1 vector load of eids + 1 wide gather of srcs per
// 64-edge chunk) + 2-edge unrolled gather pipeline (4 row-gathers in flight).
__global__ __launch_bounds__(256) void k_node(
    const ushort* __restrict__ abde, const int* __restrict__ row_ptr,
    const int* __restrict__ csr_eid, const int* __restrict__ esrc,
    float* __restrict__ out_e, ushort* __restrict__ h,
    float* __restrict__ partials) {
  const int tid = threadIdx.x;
  const int lane = tid & 63;
  const int wid = (blockIdx.x << 2) | (tid >> 6);
  const int nw = NODE_BLOCKS * 4;
  float s0 = 0.f, s1 = 0.f, q0 = 0.f, q1 = 0.f;
  for (int i = wid; i < N_NODES; i += nw) {
    uint32_t axu = *(const uint32_t*)(abde + (size_t)i * 512 + 2 * lane);        // Ax
    uint32_t dxu = *(const uint32_t*)(abde + (size_t)i * 512 + 256 + 2 * lane);  // Dx
    float ax0 = bf2f(axu & 0xffffu), ax1 = bf2f(axu >> 16);
    float dx0 = bf2f(dxu & 0xffffu), dx1 = bf2f(dxu >> 16);
    float n0 = 0.f, n1 = 0.f, d0 = 0.f, d1 = 0.f;
    const int k0 = row_ptr[i], ke = row_ptr[i + 1];
    for (int base = k0; base < ke; base += 64) {
      const int cnt = min(64, ke - base);
      int eidv = 0, srcv = 0;
      if (lane < cnt) {
        eidv = csr_eid[base + lane];   // contiguous: one coalesced load
        srcv = esrc[eidv];             // one 64-wide gather (L2)
      }
      int j = 0;
      for (; j + 2 <= cnt; j += 2) {
        int eA = __shfl(eidv, j),     sA = __shfl(srcv, j);
        int eB = __shfl(eidv, j + 1), sB = __shfl(srcv, j + 1);
        // issue all 4 row-gathers before consuming any
        uint32_t exA = *(const uint32_t*)(abde + (size_t)sA * 512 + 384 + 2 * lane);
        uint32_t bxA = *(const uint32_t*)(abde + (size_t)sA * 512 + 128 + 2 * lane);
        uint32_t exB = *(const uint32_t*)(abde + (size_t)sB * 512 + 384 + 2 * lane);
        uint32_t bxB = *(const uint32_t*)(abde + (size_t)sB * 512 + 128 + 2 * lane);
        float e0 = dx0 + bf2f(exA & 0xffffu);
        float e1 = dx1 + bf2f(exA >> 16);
        *(float2*)(out_e + (size_t)eA * 128 + 2 * lane) = make_float2(e0, e1);
        float sg0 = 1.f / (1.f + __expf(-e0));
        float sg1 = 1.f / (1.f + __expf(-e1));
        n0 += sg0 * bf2f(bxA & 0xffffu);
        n1 += sg1 * bf2f(bxA >> 16);
        d0 += sg0; d1 += sg1;
        float f0 = dx0 + bf2f(exB & 0xffffu);
        float f1 = dx1 + bf2f(exB >> 16);
        *(float2*)(out_e + (size_t)eB * 128 + 2 * lane) = make_float2(f0, f1);
        float tg0 = 1.f / (1.f + __expf(-f0));
        float tg1 = 1.f / (1.f + __expf(-f1));
        n0 += tg0 * bf2f(bxB & 0xffffu);
        n1 += tg1 * bf2f(bxB >> 16);
        d0 += tg0; d1 += tg1;
      }
      if (j < cnt) {
        int eA = __shfl(eidv, j), sA = __shfl(srcv, j);
        uint32_t exA = *(const uint32_t*)(abde + (size_t)sA * 512 + 384 + 2 * lane);
        uint32_t bxA = *(const uint32_t*)(abde + (size_t)sA * 512 + 128 + 2 * lane);
        float e0 = dx0 + bf2f(exA & 0xffffu);
        float e1 = dx1 + bf2f(exA >> 16);
        *(float2*)(out_e + (size_t)eA * 128 + 2 * lane) = make_float2(e0, e1);
        float sg0 = 1.f / (1.f + __expf(-e0));
        float sg1 = 1.f / (1.f + __expf(-e1));
        n0 += sg0 * bf2f(bxA & 0xffffu);
        n1 += sg1 * bf2f(bxA >> 16);
        d0 += sg0; d1 += sg1;
      }
    }
    float h0 = ax0 + n0 / (d0 + AGG_EPS);
    float h1 = ax1 + n1 / (d1 + AGG_EPS);
    *(uint32_t*)(h + (size_t)i * 128 + 2 * lane) = f2bf(h0) | (f2bf(h1) << 16);
    s0 += h0; s1 += h1; q0 += h0 * h0; q1 += h1 * h1;
  }
  __shared__ float red[256 * 4];
  red[tid] = s0; red[256 + tid] = s1; red[512 + tid] = q0; red[768 + tid] = q1;
  __syncthreads();
  if (tid < 64) {
    float vs0 = red[tid] + red[tid + 64] + red[tid + 128] + red[tid + 192];
    float vs1 = red[256 + tid] + red[256 + tid + 64] + red[256 + tid + 128] + red[256 + tid + 192];
    float vq0 = red[512 + tid] + red[512 + tid + 64] + red[512 + tid + 128] + red[512 + tid + 192];
    float vq1 = red[768 + tid] + red[768 + tid + 64] + red[768 + tid + 128] + red[768 + tid + 192];
    float* p = partials + blockIdx.x * 256;
    p[2 * tid] = vs0;
    p[2 * tid + 1] = vs1;
    p[128 + 2 * tid] = vq0;
    p[128 + 2 * tid + 1] = vq1;
  }
}

// ---------------- K6a: partials 2048 -> 64 (coalesced) ----------------
__global__ __launch_bounds__(256) void k_stats1(const float* __restrict__ partials,
                                                float* __restrict__ out2) {
  int t = threadIdx.x, b = blockIdx.x;  // 64 blocks
  float s = 0.f;
#pragma unroll
  for (int j = 0; j < 32; ++j) s += partials[(b * 32 + j) * 256 + t];
  out2[b * 256 + t] = s;
}

// ---------------- K6b: 64 -> stats ----------------
__global__ __launch_bounds__(128) void k_stats2(const float* __restrict__ out2,
                                                float* __restrict__ stats) {
  int c = threadIdx.x;
  float s = 0.f, q = 0.f;
#pragma unroll
  for (int b = 0; b < 64; ++b) {
    s += out2[b * 256 + c];
    q += out2[b * 256 + 128 + c];
  }
  float mean = s * (1.f / (float)N_NODES);
  float var = q * (1.f / (float)N_NODES) - mean * mean;
  stats[c] = mean;
  stats[128 + c] = rsqrtf(var + BN_EPS);
}

// ---------------- K7: normalize + ReLU ----------------
__global__ __launch_bounds__(256) void k_final(const ushort* __restrict__ h,
    const float* __restrict__ gamma, const float* __restrict__ beta,
    const float* __restrict__ stats, float* __restrict__ out_x) {
  int idx = blockIdx.x * 256 + threadIdx.x;  // 1,600,000 units of 8 elems
  int c = (idx & 15) * 8;
  uint4 hv = *(const uint4*)(h + idx * 8);
  uint32_t hw[4] = {hv.x, hv.y, hv.z, hv.w};
  float out[8];
#pragma unroll
  for (int j = 0; j < 8; ++j) {
    uint32_t u = (j & 1) ? (hw[j >> 1] >> 16) : (hw[j >> 1] & 0xffffu);
    float hf = bf2f(u);
    int cc = c + j;
    float v = gamma[cc] * (hf - stats[cc]) * stats[128 + cc] + beta[cc];
    out[j] = fmaxf(v, 0.f);
  }
  *(float4*)(out_x + idx * 8) = make_float4(out[0], out[1], out[2], out[3]);
  *(float4*)(out_x + idx * 8 + 4) = make_float4(out[4], out[5], out[6], out[7]);
}

extern "C" void kernel_launch(void* const* d_in, const int* in_sizes, int n_in,
                              void* d_out, int out_size, void* d_ws, size_t ws_size,
                              hipStream_t stream) {
  const float* x = (const float*)d_in[0];
  const int* edge_index = (const int*)d_in[2];
  const float* Wa = (const float*)d_in[3];
  const float* ba = (const float*)d_in[4];
  const float* Wb = (const float*)d_in[5];
  const float* bb = (const float*)d_in[6];
  const float* Wd = (const float*)d_in[7];
  const float* bd = (const float*)d_in[8];
  const float* We = (const float*)d_in[9];
  const float* be = (const float*)d_in[10];
  const float* gamma = (const float*)d_in[11];
  const float* beta = (const float*)d_in[12];

  const int* src = edge_index;            // edge_index[0]
  const int* dst = edge_index + N_EDGES;  // edge_index[1]

  // workspace layout (bytes), all 16B-aligned; total ~132.7 MB
  char* w = (char*)d_ws;
  ushort* wt      = (ushort*)(w);               // 131072
  float*  biasc   = (float*)(w + 131072);       // 2048
  ushort* abde    = (ushort*)(w + 133120);      // 102,400,000
  ushort* hbuf    = (ushort*)(w + 102533120);   // 25,600,000
  int*    cnt     = (int*)(w + 128133120);      // 400,000
  int*    row_ptr = (int*)(w + 128533120);      // 400,128
  int*    cursor  = (int*)(w + 128933248);      // 400,000
  int*    csr_eid = (int*)(w + 129333248);      // 1,280,000
  float*  partials= (float*)(w + 130613248);    // 2,097,152
  float*  stats   = (float*)(w + 132710400);    // 1024

  // overlays (no ws growth):
  int*   bsum = (int*)partials;
  int*   boff = (int*)(partials + 512);
  float* out2 = (float*)cnt;  // dead after k_scan3; fully overwritten by k_stats1

  float* out_x = (float*)d_out;
  float* out_e = out_x + (size_t)N_NODES * DIM;

  k_prep<<<256, 256, 0, stream>>>(Wa, ba, Wb, bb, Wd, bd, We, be, wt, biasc, (uint4*)cnt);
  k_gemm<<<1563, 256, 0, stream>>>(x, wt, biasc, abde);
  k_count<<<(N_EDGES + 255) / 256, 256, 0, stream>>>(dst, cnt);
  k_bsum<<<SCAN_BLOCKS, 256, 0, stream>>>(cnt, bsum);
  k_scanb<<<1, 512, 0, stream>>>(bsum, boff, row_ptr);
  k_scan3<<<SCAN_BLOCKS, 256, 0, stream>>>(cnt, boff, row_ptr, cursor);
  k_scatter<<<(N_EDGES + 255) / 256, 256, 0, stream>>>(dst, cursor, csr_eid);
  k_node<<<NODE_BLOCKS, 256, 0, stream>>>(abde, row_ptr, csr_eid, src, out_e, hbuf, partials);
  k_stats1<<<64, 256, 0, stream>>>(partials, out2);
  k_stats2<<<1, 128, 0, stream>>>(out2, stats);
  k_final<<<6250, 256, 0, stream>>>(hbuf, gamma, beta, stats, out_x);
}